// Round 9
// baseline (614.475 us; speedup 1.0000x reference)
//
#include <hip/hip_runtime.h>
#include <hip/hip_fp16.h>
#include <math.h>

#define NN 50000
#define EE 800000
#define HIDDEN 128
#define NGRAPH 50
#define GEMM_TILES ((NN + 63) / 64)
#define NB_ATTN 12500

typedef _Float16 half8 __attribute__((ext_vector_type(8)));
typedef _Float16 half2v __attribute__((ext_vector_type(2)));
typedef float f32x4 __attribute__((ext_vector_type(4)));
typedef unsigned long long u64;

// ---------------- CSR degree count (+rank capture) + weight transpose ----------------
__global__ void k_degprep(const int* __restrict__ eidx, int* __restrict__ cnt,
                          int* __restrict__ rank,
                          const float* __restrict__ Wq, const float* __restrict__ Wk,
                          const float* __restrict__ Wv, const float* __restrict__ Ws,
                          _Float16* __restrict__ wt) {
    int b = blockIdx.x;
    int t = threadIdx.x;
    if (b < 3125) {
        int e = b * 256 + t;
        if (e < EE) {
            int p = atomicAdd(&cnt[eidx[EE + e]], 1);
            rank[e] = p;
        }
    } else {
        int idx = (b - 3125) * 256 + t;   // 12 * 16384 fp16 transposed weights
        if (idx < 12 * 16384) {
            int mat = idx >> 14;
            int l = mat >> 2, w = mat & 3;
            int nk = idx & 16383;
            int n = nk >> 7, k = nk & 127;
            const float* W = (w == 0 ? Wq : w == 1 ? Wk : w == 2 ? Wv : Ws) + (size_t)l * 16384;
            wt[idx] = (_Float16)W[k * 128 + n];
        }
    }
}

// scan + housekeeping: exclusive-scan deg->row_ptr (4 elems/thread), zero cnt,
// zero bn_acc3 / gsum / gcnt
__global__ void k_scan(int* __restrict__ cnt, int* __restrict__ row_ptr,
                       float* __restrict__ bn_acc3, float* __restrict__ gsum,
                       int* __restrict__ gcnt) {
    __shared__ int wsum[16];
    __shared__ int carry_s;
    int t = threadIdx.x;
    int lane = t & 63, w = t >> 6;
    if (t < 768) bn_acc3[t] = 0.f;
    if (t < 64) { gsum[t] = 0.f; gcnt[t] = 0; }
    if (t == 0) carry_s = 0;
    __syncthreads();
    for (int base = 0; base < NN; base += 4096) {
        int i0 = base + t * 4;
        int v[4];
#pragma unroll
        for (int j = 0; j < 4; j++) v[j] = (i0 + j < NN) ? cnt[i0 + j] : 0;
        int s4 = v[0] + v[1] + v[2] + v[3];
        int s = s4;
#pragma unroll
        for (int o = 1; o < 64; o <<= 1) {
            int u = __shfl_up(s, o);
            if (lane >= o) s += u;
        }
        if (lane == 63) wsum[w] = s;
        __syncthreads();
        if (w == 0) {
            int ws = (lane < 16) ? wsum[lane] : 0;
#pragma unroll
            for (int o = 1; o < 16; o <<= 1) {
                int u = __shfl_up(ws, o);
                if (lane >= o) ws += u;
            }
            if (lane < 16) wsum[lane] = ws;
        }
        __syncthreads();
        int wpre = (w == 0) ? 0 : wsum[w - 1];
        int run = carry_s + wpre + s - s4;
#pragma unroll
        for (int j = 0; j < 4; j++) {
            if (i0 + j < NN) { row_ptr[i0 + j] = run; cnt[i0 + j] = 0; run += v[j]; }
        }
        __syncthreads();
        if (t == 0) carry_s += wsum[15];
        __syncthreads();
    }
    if (t == 0) row_ptr[NN] = carry_s;
}

// ---- GEMM tile body via f16 MFMA: q fp16 out, xr fp32 out; k,v packed fp8 e4m3 ----
__device__ __forceinline__ void gemm_tile(
    const float* __restrict__ X, const _Float16* __restrict__ wt,
    const float* __restrict__ bq, const float* __restrict__ bk,
    const float* __restrict__ bv, const float* __restrict__ bs,
    const float* ab_s, int use_ab, _Float16 (*xs)[136],
    _Float16* __restrict__ qo, unsigned int* __restrict__ kvb, float* __restrict__ xro,
    int m0)
{
    int t = threadIdx.x;
    int lane = t & 63, wid = t >> 6;
#pragma unroll
    for (int i = 0; i < 8; ++i) {
        int f = t + 256 * i;          // float4 index within 64x32
        int r = f >> 5, c4 = (f & 31) << 2;
        float4 val = make_float4(0.f, 0.f, 0.f, 0.f);
        if (m0 + r < NN) val = *(const float4*)&X[(size_t)(m0 + r) * 128 + c4];
        if (use_ab) {
            float4 a = *(const float4*)&ab_s[c4];
            float4 bb = *(const float4*)&ab_s[128 + c4];
            float z;
            z = fmaf(val.x, a.x, bb.x); val.x = z > 0.f ? z : expm1f(z);
            z = fmaf(val.y, a.y, bb.y); val.y = z > 0.f ? z : expm1f(z);
            z = fmaf(val.z, a.z, bb.z); val.z = z > 0.f ? z : expm1f(z);
            z = fmaf(val.w, a.w, bb.w); val.w = z > 0.f ? z : expm1f(z);
        }
        _Float16* dst = &xs[r][c4];
        dst[0] = (_Float16)val.x; dst[1] = (_Float16)val.y;
        dst[2] = (_Float16)val.z; dst[3] = (_Float16)val.w;
    }
    __syncthreads();
    int quad = lane >> 4, l15 = lane & 15;
    int mrow = wid * 16;
    half8 afrag[4];
#pragma unroll
    for (int kk = 0; kk < 4; kk++)
        afrag[kk] = *(const half8*)&xs[mrow + l15][kk * 32 + quad * 8];

#pragma unroll
    for (int nt = 0; nt < 8; nt++) {
        int c = nt * 16 + l15;
        f32x4 acc[4];
#pragma unroll
        for (int w = 0; w < 4; w++) acc[w] = (f32x4){0.f, 0.f, 0.f, 0.f};
#pragma unroll
        for (int kk = 0; kk < 4; kk++) {
            half8 bf[4];
#pragma unroll
            for (int w = 0; w < 4; w++)
                bf[w] = *(const half8*)&wt[(size_t)w * 16384 + c * 128 + kk * 32 + quad * 8];
#pragma unroll
            for (int w = 0; w < 4; w++)
                acc[w] = __builtin_amdgcn_mfma_f32_16x16x32_f16(afrag[kk], bf[w], acc[w], 0, 0, 0);
        }
        float bqv = bq[c], bkv = bk[c], bvv = bv[c], bsv = bs[c];
        int nodebase = m0 + mrow + quad * 4;
#pragma unroll
        for (int r = 0; r < 4; r++) {
            int node = nodebase + r;
            bool ok = node < NN;
            float qv = acc[0][r] + bqv;
            float xv = acc[3][r] + bsv;
            float kf = acc[1][r] + bkv;
            float vf = acc[2][r] + bvv;
            float kf1 = __shfl_xor(kf, 1);
            float vf1 = __shfl_xor(vf, 1);
            if (ok) {
                qo[(size_t)node * 128 + c] = (_Float16)qv;
                xro[(size_t)node * 128 + c] = xv;
                if (!(lane & 1)) {
                    int w2 = __builtin_amdgcn_cvt_pk_fp8_f32(kf, kf1, 0, false);
                    w2 = __builtin_amdgcn_cvt_pk_fp8_f32(vf, vf1, w2, true);
                    kvb[(size_t)node * 64 + (c >> 1)] = (unsigned int)w2;
                }
            }
        }
    }
}

// ---- layer-0 GEMM fused with CSR scatter (independent work, union grid) ----
// v9: 8B edge record {low32: src, high32: half2 attrs}, nontemporal store
// (stream-out; keeps L2 for kvb), atomic-free pos = row_ptr[d] + rank[e].
__global__ __launch_bounds__(256) void k_gemm0scat(
    const float* __restrict__ X, const _Float16* __restrict__ wt,
    const float* __restrict__ bq, const float* __restrict__ bk,
    const float* __restrict__ bv, const float* __restrict__ bs,
    _Float16* __restrict__ qo, unsigned int* __restrict__ kvb, float* __restrict__ xro,
    const int* __restrict__ eidx, const float* __restrict__ eattr,
    const int* __restrict__ row_ptr, const int* __restrict__ rank,
    u64* __restrict__ erec)
{
    __shared__ _Float16 xs[64][136];
    int b = blockIdx.x;
    if (b < GEMM_TILES) {
        gemm_tile(X, wt, bq, bk, bv, bs, nullptr, 0, xs, qo, kvb, xro, b * 64);
    } else {
        int e = (b - GEMM_TILES) * 256 + threadIdx.x;
        if (e < EE) {
            int d = eidx[EE + e];
            int s = eidx[e];
            int rk = rank[e];
            float2 ea = *(const float2*)&eattr[2 * (size_t)e];
            union { _Float16 h[2]; unsigned int u; } cv;
            cv.h[0] = (_Float16)ea.x; cv.h[1] = (_Float16)ea.y;
            int pos = row_ptr[d] + rk;
            u64 rec = ((u64)cv.u << 32) | (unsigned int)s;
            __builtin_nontemporal_store(rec, &erec[pos]);
        }
    }
}

// ---- layers 1,2 GEMM (BN affine+ELU on input from bn_acc stats) ----
__global__ __launch_bounds__(256) void k_gemm4(
    const float* __restrict__ X, const _Float16* __restrict__ wt,
    const float* __restrict__ bq, const float* __restrict__ bk,
    const float* __restrict__ bv, const float* __restrict__ bs,
    const float* __restrict__ bn_acc, const float* __restrict__ gamma,
    const float* __restrict__ beta,
    _Float16* __restrict__ qo, unsigned int* __restrict__ kvb, float* __restrict__ xro)
{
    __shared__ _Float16 xs[64][136];
    __shared__ float ab_s[256];
    int t = threadIdx.x;
    if (t < 128) {
        float mu = bn_acc[t] * (1.f / NN);
        float var = bn_acc[128 + t] * (1.f / NN) - mu * mu;
        float inv = rsqrtf(var + 1e-5f);
        float a = inv * gamma[t];
        ab_s[t] = a;
        ab_s[128 + t] = beta[t] - mu * a;
    }
    __syncthreads();
    gemm_tile(X, wt, bq, bk, bv, bs, ab_s, 1, xs, qo, kvb, xro, blockIdx.x * 64);
}

// 16-lane (per-head) sum via DPP row rotations — VALU-only, no DS-pipe ops.
__device__ __forceinline__ float row_sum16(float p) {
    p += __int_as_float(__builtin_amdgcn_update_dpp(0, __float_as_int(p), 0x128, 0xF, 0xF, true)); // row_ror:8
    p += __int_as_float(__builtin_amdgcn_update_dpp(0, __float_as_int(p), 0x124, 0xF, 0xF, true)); // row_ror:4
    p += __int_as_float(__builtin_amdgcn_update_dpp(0, __float_as_int(p), 0x122, 0xF, 0xF, true)); // row_ror:2
    p += __int_as_float(__builtin_amdgcn_update_dpp(0, __float_as_int(p), 0x121, 0xF, 0xF, true)); // row_ror:1
    return p;
}

// ---------------- attention + gate + BN-stats (one wave per dst node) ----------------
// v9: fp16 q read, 8B edge records, v3-proven algebraic fold (scale*log2e into
// q -> exp2 direct; Sum(w*e) factored into sA/sB/den, folded once at the end).
// v8's double-buffered gathers + DPP reduce + coalesced BN partials retained.
__global__ __launch_bounds__(256) void k_attn(
    const _Float16* __restrict__ q, const unsigned int* __restrict__ kvb,
    const float* __restrict__ xr,
    const u64* __restrict__ erec,
    const int* __restrict__ row_ptr,
    const float* __restrict__ We, const float* __restrict__ be,
    const float* __restrict__ Wb,
    float* __restrict__ out2, float* __restrict__ bnp)
{
    __shared__ u64 es[4][64];
    int t = threadIdx.x;
    int lane = t & 63;
    int wid = t >> 6;
    int n = blockIdx.x * 4 + wid;          // one node per wave, exact cover
    int ch = lane * 2;
    float2 we0 = *(const float2*)&We[ch];
    float2 we1 = *(const float2*)&We[128 + ch];
    float2 beL = *(const float2*)&be[ch];
    const float S2 = 0.17677669529663687f * 1.4426950408889634f;  // (1/sqrt(32))*log2(e)

    int rs = __builtin_amdgcn_readfirstlane(row_ptr[n]);
    int re = __builtin_amdgcn_readfirstlane(row_ptr[n + 1]);
    half2v qh = *(const half2v*)&q[(size_t)n * 128 + ch];
    float2 xv = *(const float2*)&xr[(size_t)n * 128 + ch];   // prefetch early
    float2 qs; qs.x = (float)qh[0] * S2; qs.y = (float)qh[1] * S2;
    float qw0 = qs.x * we0.x + qs.y * we0.y;
    float qw1 = qs.x * we1.x + qs.y * we1.y;
    float qb0 = qs.x * beL.x + qs.y * beL.y;
    float den = 0.f, sA = 0.f, sB = 0.f, ax = 0.f, ay = 0.f;

    for (int cb = rs; cb < re; cb += 64) {
        int cnum = re - cb; if (cnum > 64) cnum = 64;
        int mi = cb + lane;
        if (mi < re) es[wid][lane] = erec[mi];   // coalesced 8B; same-wave LDS in order
        const unsigned int* es32 = (const unsigned int*)&es[wid][0];
        int cm1 = cnum - 1;
        int ng = (cnum + 7) >> 3;                // padded groups of 8 (clamp+mask)
        unsigned int kkA[8], kkB[8];

#define LOAD8(KK, B0) do {                                                   \
        _Pragma("unroll")                                                    \
        for (int j = 0; j < 8; j++) {                                        \
            int o = (B0) + j; int oc = o < cm1 ? o : cm1;                    \
            unsigned int s = es32[oc * 2];                                   \
            KK[j] = kvb[(size_t)s * 64 + lane];                              \
        }                                                                    \
    } while (0)

#define COMP8(KK, B0) do {                                                   \
        _Pragma("unroll")                                                    \
        for (int j = 0; j < 8; j++) {                                        \
            int o = (B0) + j; int oc = o < cm1 ? o : cm1;                    \
            union { unsigned int u; _Float16 h[2]; } cv;                     \
            cv.u = es32[oc * 2 + 1];                                         \
            float eax = (float)cv.h[0], eay = (float)cv.h[1];                \
            auto kf = __builtin_amdgcn_cvt_pk_f32_fp8((int)KK[j], false);    \
            auto vf = __builtin_amdgcn_cvt_pk_f32_fp8((int)KK[j], true);     \
            float p = qs.x * kf[0];                                          \
            p = fmaf(qs.y, kf[1], p);                                        \
            p = fmaf(eax, qw0, p);                                           \
            p = fmaf(eay, qw1, p);                                           \
            p += qb0;                                                        \
            p = row_sum16(p);                                                \
            float exv = (o < cnum) ? __builtin_amdgcn_exp2f(p) : 0.f;        \
            den += exv;                                                      \
            sA = fmaf(exv, eax, sA);                                         \
            sB = fmaf(exv, eay, sB);                                         \
            ax = fmaf(exv, vf[0], ax);                                       \
            ay = fmaf(exv, vf[1], ay);                                       \
        }                                                                    \
    } while (0)

        LOAD8(kkA, 0);
        __builtin_amdgcn_sched_barrier(0);
        int g = 0;
        for (;;) {
            if (g + 1 < ng) { LOAD8(kkB, (g + 1) * 8); __builtin_amdgcn_sched_barrier(0); }
            COMP8(kkA, g * 8);
            ++g; if (g >= ng) break;
            if (g + 1 < ng) { LOAD8(kkA, (g + 1) * 8); __builtin_amdgcn_sched_barrier(0); }
            COMP8(kkB, g * 8);
            ++g; if (g >= ng) break;
        }
#undef LOAD8
#undef COMP8
    }

    // fold Sum(w*e) back in
    float axT = ax + sA * we0.x + sB * we1.x + den * beL.x;
    float ayT = ay + sA * we0.y + sB * we1.y + den * beL.y;
    float rden = 1.f / (den + 1e-16f);
    float axs = axT * rden, ays = ayT * rden;
    // beta gate
    float2 wb_o = *(const float2*)&Wb[ch];
    float2 wb_r = *(const float2*)&Wb[128 + ch];
    float2 wb_d = *(const float2*)&Wb[256 + ch];
    float gp = axs * wb_o.x + ays * wb_o.y + xv.x * wb_r.x + xv.y * wb_r.y
             + (axs - xv.x) * wb_d.x + (ays - xv.y) * wb_d.y;
    gp = row_sum16(gp);
    gp += __shfl_xor(gp, 16);
    gp += __shfl_xor(gp, 32);
    float gate = 1.f / (1.f + __expf(-gp));
    float ox = gate * xv.x + (1.f - gate) * axs;
    float oy = gate * xv.y + (1.f - gate) * ays;
    *(float2*)&out2[(size_t)n * 128 + ch] = make_float2(ox, oy);

    // block-level BN partial reduce -> coalesced per-block record [block][256]
    __shared__ float s_sum[2][256], s_sq[2][256];
    s_sum[0][t] = ox; s_sum[1][t] = oy;
    s_sq[0][t] = ox * ox;  s_sq[1][t] = oy * oy;
    __syncthreads();
    if (t < 64) {
        float sx = s_sum[0][t] + s_sum[0][64 + t] + s_sum[0][128 + t] + s_sum[0][192 + t];
        float sy = s_sum[1][t] + s_sum[1][64 + t] + s_sum[1][128 + t] + s_sum[1][192 + t];
        float qx = s_sq[0][t] + s_sq[0][64 + t] + s_sq[0][128 + t] + s_sq[0][192 + t];
        float qy = s_sq[1][t] + s_sq[1][64 + t] + s_sq[1][128 + t] + s_sq[1][192 + t];
        float2* bp = (float2*)&bnp[(size_t)blockIdx.x * 256];
        bp[t] = make_float2(sx, sy);          // channels 2t, 2t+1
        bp[64 + t] = make_float2(qx, qy);     // channels 128+2t, 129+2t
    }
}

// ---- reduce per-block BN partials [12500][256] -> bn_acc (coalesced, low-contention) ----
__global__ __launch_bounds__(256) void k_bnred(const float* __restrict__ part,
                                               float* __restrict__ bn_acc) {
    int t = threadIdx.x;
    int g = blockIdx.x;                       // 250 blocks x 50 records
    float s = 0.f;
    for (int r = g * 50; r < g * 50 + 50; ++r)
        s += part[(size_t)r * 256 + t];
    atomicAdd(&bn_acc[t], s);                 // 64k atomics over 256 addrs: ~2us
}

// ------- readout: BN affine+ELU+dot(Wout); 313 blocks x 10 chunks to keep
//         gsum/gcnt atomic contention low; LDS per-graph accumulate, one flush -------
__global__ __launch_bounds__(256) void k_pool(const float* __restrict__ x,
                                              const float* __restrict__ bn_acc,
                                              const float* __restrict__ gamma,
                                              const float* __restrict__ beta,
                                              const float* __restrict__ Wout,
                                              const int* __restrict__ batch,
                                              float* __restrict__ gsum, int* __restrict__ gcnt) {
    __shared__ float lsum[NGRAPH];
    __shared__ int lcnt[NGRAPH];
    __shared__ float ab_s[256];
    int t = threadIdx.x;
    if (t < NGRAPH) { lsum[t] = 0.f; lcnt[t] = 0; }
    if (t < 128) {
        float mu = bn_acc[t] * (1.f / NN);
        float var = bn_acc[128 + t] * (1.f / NN) - mu * mu;
        float inv = rsqrtf(var + 1e-5f);
        float a = inv * gamma[t];
        ab_s[t] = a;
        ab_s[128 + t] = beta[t] - mu * a;
    }
    __syncthreads();
    int lane = t & 63;
    int wid = t >> 6;
    int ch = lane * 2;
    float2 wo = *(const float2*)&Wout[ch];
    float2 a = *(const float2*)&ab_s[ch];
    float2 b = *(const float2*)&ab_s[128 + ch];
    for (int chunk = 0; chunk < 10; ++chunk) {
        int base = blockIdx.x * 160 + chunk * 16 + wid * 4;
        float2 xv[4];
#pragma unroll
        for (int i = 0; i < 4; i++) {          // issue all 4 loads before any use
            int n = base + i;
            xv[i] = (n < NN) ? *(const float2*)&x[(size_t)n * 128 + ch]
                             : make_float2(0.f, 0.f);
        }
#pragma unroll
        for (int i = 0; i < 4; i++) {
            int n = base + i;
            if (n < NN) {
                float z0 = fmaf(xv[i].x, a.x, b.x); z0 = z0 > 0.f ? z0 : expm1f(z0);
                float z1 = fmaf(xv[i].y, a.y, b.y); z1 = z1 > 0.f ? z1 : expm1f(z1);
                float p = z0 * wo.x + z1 * wo.y;
                p += __shfl_xor(p, 1);
                p += __shfl_xor(p, 2);
                p += __shfl_xor(p, 4);
                p += __shfl_xor(p, 8);
                p += __shfl_xor(p, 16);
                p += __shfl_xor(p, 32);
                if (lane == 0) {
                    int g = batch[n];
                    atomicAdd(&lsum[g], p);
                    atomicAdd(&lcnt[g], 1);
                }
            }
        }
    }
    __syncthreads();
    if (t < NGRAPH && lcnt[t] > 0) {
        atomicAdd(&gsum[t], lsum[t]);
        atomicAdd(&gcnt[t], lcnt[t]);
    }
}

__global__ void k_final(const float* __restrict__ gsum, const int* __restrict__ gcnt,
                        const float* __restrict__ bout, const float* __restrict__ obias,
                        float* __restrict__ out) {
    int g = threadIdx.x;
    if (g < NGRAPH) out[g] = gsum[g] / fmaxf((float)gcnt[g], 1.f) + bout[0] + obias[0];
}

extern "C" void kernel_launch(void* const* d_in, const int* in_sizes, int n_in,
                              void* d_out, int out_size, void* d_ws, size_t ws_size,
                              hipStream_t stream) {
    const float* x_in       = (const float*)d_in[0];
    const int* eidx         = (const int*)d_in[1];
    const float* eattr      = (const float*)d_in[2];
    const int* batch        = (const int*)d_in[3];
    const float* Wq         = (const float*)d_in[4];
    const float* bq         = (const float*)d_in[5];
    const float* Wk         = (const float*)d_in[6];
    const float* bk         = (const float*)d_in[7];
    const float* Wv         = (const float*)d_in[8];
    const float* bv         = (const float*)d_in[9];
    const float* We         = (const float*)d_in[10];
    const float* be         = (const float*)d_in[11];
    const float* Wskip      = (const float*)d_in[12];
    const float* bskip      = (const float*)d_in[13];
    const float* Wbeta      = (const float*)d_in[14];
    const float* bn_gamma   = (const float*)d_in[15];
    const float* bn_beta    = (const float*)d_in[16];
    const float* Wout       = (const float*)d_in[17];
    const float* bout       = (const float*)d_in[18];
    const float* obias      = (const float*)d_in[19];
    float* out = (float*)d_out;

    char* ws = (char*)d_ws;
    size_t off = 0;
    auto alloc = [&](size_t bytes) -> void* {
        off = (off + 255) & ~(size_t)255;
        void* p = ws + off;
        off += bytes;
        return p;
    };
    const size_t NF = (size_t)NN * 128 * sizeof(float);
    float* xbuf    = (float*)alloc(NF);
    _Float16* qb   = (_Float16*)alloc((size_t)NN * 128 * sizeof(_Float16));
    float* xrb     = (float*)alloc(NF);
    unsigned int* kvb = (unsigned int*)alloc((size_t)NN * 64 * sizeof(unsigned int));
    _Float16* wt   = (_Float16*)alloc((size_t)12 * 16384 * sizeof(_Float16));
    int* row_ptr   = (int*)alloc((NN + 1) * sizeof(int));
    int* cnt       = (int*)alloc(NN * sizeof(int));
    int* rank      = (int*)alloc(EE * sizeof(int));
    u64* erec      = (u64*)alloc((size_t)EE * sizeof(u64));
    float* bn_acc3 = (float*)alloc(3 * 256 * sizeof(float));
    float* bnpart  = (float*)alloc((size_t)NB_ATTN * 256 * sizeof(float));
    float* gsum    = (float*)alloc(64 * sizeof(float));
    int* gcnt      = (int*)alloc(64 * sizeof(int));
    (void)ws_size; (void)n_in; (void)in_sizes; (void)out_size;

    // ---- CSR degree + rank + weight prep, scan (also zeroes aux) ----
    hipMemsetAsync(cnt, 0, NN * sizeof(int), stream);
    k_degprep<<<3125 + 768, 256, 0, stream>>>(eidx, cnt, rank, Wq, Wk, Wv, Wskip, wt);
    k_scan<<<1, 1024, 0, stream>>>(cnt, row_ptr, bn_acc3, gsum, gcnt);

    // ---- layer 0 GEMM + CSR scatter fused (independent work) ----
    k_gemm0scat<<<GEMM_TILES + 3125, 256, 0, stream>>>(
        x_in, wt, bq, bk, bv, bskip, qb, kvb, xrb,
        eidx, eattr, row_ptr, rank, erec);
    k_attn<<<NB_ATTN, 256, 0, stream>>>(
        qb, kvb, xrb, erec, row_ptr,
        We, be, Wbeta, xbuf, bnpart);
    k_bnred<<<250, 256, 0, stream>>>(bnpart, bn_acc3);

    // ---- layers 1,2 ----
    for (int l = 1; l < 3; ++l) {
        k_gemm4<<<GEMM_TILES, 256, 0, stream>>>(
            xbuf, wt + (size_t)l * 65536,
            bq + l * 128, bk + l * 128, bv + l * 128, bskip + l * 128,
            bn_acc3 + (l - 1) * 256, bn_gamma + (l - 1) * 128, bn_beta + (l - 1) * 128,
            qb, kvb, xrb);
        k_attn<<<NB_ATTN, 256, 0, stream>>>(
            qb, kvb, xrb, erec, row_ptr,
            We + (size_t)l * 256, be + l * 128, Wbeta + (size_t)l * 384,
            xbuf, bnpart);
        k_bnred<<<250, 256, 0, stream>>>(bnpart, bn_acc3 + l * 256);
    }

    // ---- readout (BN affine+ELU of layer-2 fused in) ----
    k_pool<<<313, 256, 0, stream>>>(xbuf, bn_acc3 + 2 * 256,
                                    bn_gamma + 2 * 128, bn_beta + 2 * 128,
                                    Wout, batch, gsum, gcnt);
    k_final<<<1, 64, 0, stream>>>(gsum, gcnt, bout, obias, out);
}

// Round 12
// 612.966 us; speedup vs baseline: 1.0025x; 1.0025x over previous
//
#include <hip/hip_runtime.h>
#include <hip/hip_fp16.h>
#include <math.h>

#define NN 50000
#define EE 800000
#define HIDDEN 128
#define NGRAPH 50
#define GEMM_TILES ((NN + 63) / 64)
#define NB_ATTN 12500
#define NSLOT 64

typedef _Float16 half8 __attribute__((ext_vector_type(8)));
typedef _Float16 half2v __attribute__((ext_vector_type(2)));
typedef float f32x4 __attribute__((ext_vector_type(4)));
typedef unsigned long long u64;

// ---------------- CSR degree count (+rank capture) + weight transpose ----------------
__global__ void k_degprep(const int* __restrict__ eidx, int* __restrict__ cnt,
                          int* __restrict__ rank,
                          const float* __restrict__ Wq, const float* __restrict__ Wk,
                          const float* __restrict__ Wv, const float* __restrict__ Ws,
                          _Float16* __restrict__ wt) {
    int b = blockIdx.x;
    int t = threadIdx.x;
    if (b < 3125) {
        int e = b * 256 + t;
        if (e < EE) {
            int p = atomicAdd(&cnt[eidx[EE + e]], 1);
            rank[e] = p;
        }
    } else {
        int idx = (b - 3125) * 256 + t;   // 12 * 16384 fp16 transposed weights
        if (idx < 12 * 16384) {
            int mat = idx >> 14;
            int l = mat >> 2, w = mat & 3;
            int nk = idx & 16383;
            int n = nk >> 7, k = nk & 127;
            const float* W = (w == 0 ? Wq : w == 1 ? Wk : w == 2 ? Wv : Ws) + (size_t)l * 16384;
            wt[idx] = (_Float16)W[k * 128 + n];
        }
    }
}

// scan + housekeeping: exclusive-scan deg->row_ptr (4 elems/thread), zero cnt,
// zero bns3 (3 layers x 64 slots x 256), gsum/gcnt, pool-done counter
__global__ void k_scan(int* __restrict__ cnt, int* __restrict__ row_ptr,
                       float* __restrict__ bns3, float* __restrict__ gsum,
                       int* __restrict__ gcnt, int* __restrict__ pdone) {
    __shared__ int wsum[16];
    __shared__ int carry_s;
    int t = threadIdx.x;
    int lane = t & 63, w = t >> 6;
    for (int i = t; i < 3 * NSLOT * 256; i += 1024) bns3[i] = 0.f;
    if (t < 64) { gsum[t] = 0.f; gcnt[t] = 0; }
    if (t == 0) { carry_s = 0; *pdone = 0; }
    __syncthreads();
    for (int base = 0; base < NN; base += 4096) {
        int i0 = base + t * 4;
        int v[4];
#pragma unroll
        for (int j = 0; j < 4; j++) v[j] = (i0 + j < NN) ? cnt[i0 + j] : 0;
        int s4 = v[0] + v[1] + v[2] + v[3];
        int s = s4;
#pragma unroll
        for (int o = 1; o < 64; o <<= 1) {
            int u = __shfl_up(s, o);
            if (lane >= o) s += u;
        }
        if (lane == 63) wsum[w] = s;
        __syncthreads();
        if (w == 0) {
            int ws = (lane < 16) ? wsum[lane] : 0;
#pragma unroll
            for (int o = 1; o < 16; o <<= 1) {
                int u = __shfl_up(ws, o);
                if (lane >= o) ws += u;
            }
            if (lane < 16) wsum[lane] = ws;
        }
        __syncthreads();
        int wpre = (w == 0) ? 0 : wsum[w - 1];
        int run = carry_s + wpre + s - s4;
#pragma unroll
        for (int j = 0; j < 4; j++) {
            if (i0 + j < NN) { row_ptr[i0 + j] = run; cnt[i0 + j] = 0; run += v[j]; }
        }
        __syncthreads();
        if (t == 0) carry_s += wsum[15];
        __syncthreads();
    }
    if (t == 0) row_ptr[NN] = carry_s;
}

// ---- GEMM tile body via f16 MFMA: q fp16 out, xr fp32 out; k,v packed fp8 e4m3 ----
__device__ __forceinline__ void gemm_tile(
    const float* __restrict__ X, const _Float16* __restrict__ wt,
    const float* __restrict__ bq, const float* __restrict__ bk,
    const float* __restrict__ bv, const float* __restrict__ bs,
    const float* ab_s, int use_ab, _Float16 (*xs)[136],
    _Float16* __restrict__ qo, unsigned int* __restrict__ kvb, float* __restrict__ xro,
    int m0)
{
    int t = threadIdx.x;
    int lane = t & 63, wid = t >> 6;
#pragma unroll
    for (int i = 0; i < 8; ++i) {
        int f = t + 256 * i;          // float4 index within 64x32
        int r = f >> 5, c4 = (f & 31) << 2;
        float4 val = make_float4(0.f, 0.f, 0.f, 0.f);
        if (m0 + r < NN) val = *(const float4*)&X[(size_t)(m0 + r) * 128 + c4];
        if (use_ab) {
            float4 a = *(const float4*)&ab_s[c4];
            float4 bb = *(const float4*)&ab_s[128 + c4];
            float z;
            z = fmaf(val.x, a.x, bb.x); val.x = z > 0.f ? z : expm1f(z);
            z = fmaf(val.y, a.y, bb.y); val.y = z > 0.f ? z : expm1f(z);
            z = fmaf(val.z, a.z, bb.z); val.z = z > 0.f ? z : expm1f(z);
            z = fmaf(val.w, a.w, bb.w); val.w = z > 0.f ? z : expm1f(z);
        }
        _Float16* dst = &xs[r][c4];
        dst[0] = (_Float16)val.x; dst[1] = (_Float16)val.y;
        dst[2] = (_Float16)val.z; dst[3] = (_Float16)val.w;
    }
    __syncthreads();
    int quad = lane >> 4, l15 = lane & 15;
    int mrow = wid * 16;
    half8 afrag[4];
#pragma unroll
    for (int kk = 0; kk < 4; kk++)
        afrag[kk] = *(const half8*)&xs[mrow + l15][kk * 32 + quad * 8];

#pragma unroll
    for (int nt = 0; nt < 8; nt++) {
        int c = nt * 16 + l15;
        f32x4 acc[4];
#pragma unroll
        for (int w = 0; w < 4; w++) acc[w] = (f32x4){0.f, 0.f, 0.f, 0.f};
#pragma unroll
        for (int kk = 0; kk < 4; kk++) {
            half8 bf[4];
#pragma unroll
            for (int w = 0; w < 4; w++)
                bf[w] = *(const half8*)&wt[(size_t)w * 16384 + c * 128 + kk * 32 + quad * 8];
#pragma unroll
            for (int w = 0; w < 4; w++)
                acc[w] = __builtin_amdgcn_mfma_f32_16x16x32_f16(afrag[kk], bf[w], acc[w], 0, 0, 0);
        }
        float bqv = bq[c], bkv = bk[c], bvv = bv[c], bsv = bs[c];
        int nodebase = m0 + mrow + quad * 4;
#pragma unroll
        for (int r = 0; r < 4; r++) {
            int node = nodebase + r;
            bool ok = node < NN;
            float qv = acc[0][r] + bqv;
            float xv = acc[3][r] + bsv;
            float kf = acc[1][r] + bkv;
            float vf = acc[2][r] + bvv;
            float kf1 = __shfl_xor(kf, 1);
            float vf1 = __shfl_xor(vf, 1);
            if (ok) {
                qo[(size_t)node * 128 + c] = (_Float16)qv;
                xro[(size_t)node * 128 + c] = xv;
                if (!(lane & 1)) {
                    int w2 = __builtin_amdgcn_cvt_pk_fp8_f32(kf, kf1, 0, false);
                    w2 = __builtin_amdgcn_cvt_pk_fp8_f32(vf, vf1, w2, true);
                    kvb[(size_t)node * 64 + (c >> 1)] = (unsigned int)w2;
                }
            }
        }
    }
}

// ---- layer-0 GEMM fused with CSR scatter (independent work, union grid) ----
__global__ __launch_bounds__(256) void k_gemm0scat(
    const float* __restrict__ X, const _Float16* __restrict__ wt,
    const float* __restrict__ bq, const float* __restrict__ bk,
    const float* __restrict__ bv, const float* __restrict__ bs,
    _Float16* __restrict__ qo, unsigned int* __restrict__ kvb, float* __restrict__ xro,
    const int* __restrict__ eidx, const float* __restrict__ eattr,
    const int* __restrict__ row_ptr, const int* __restrict__ rank,
    u64* __restrict__ erec)
{
    __shared__ _Float16 xs[64][136];
    int b = blockIdx.x;
    if (b < GEMM_TILES) {
        gemm_tile(X, wt, bq, bk, bv, bs, nullptr, 0, xs, qo, kvb, xro, b * 64);
    } else {
        int e = (b - GEMM_TILES) * 256 + threadIdx.x;
        if (e < EE) {
            int d = eidx[EE + e];
            int s = eidx[e];
            int rk = rank[e];
            float2 ea = *(const float2*)&eattr[2 * (size_t)e];
            union { _Float16 h[2]; unsigned int u; } cv;
            cv.h[0] = (_Float16)ea.x; cv.h[1] = (_Float16)ea.y;
            int pos = row_ptr[d] + rk;
            u64 rec = ((u64)cv.u << 32) | (unsigned int)s;
            __builtin_nontemporal_store(rec, &erec[pos]);
        }
    }
}

// ---- layers 1,2 GEMM: BN affine+ELU on input; stats summed from 64-slot partials ----
__global__ __launch_bounds__(256) void k_gemm4(
    const float* __restrict__ X, const _Float16* __restrict__ wt,
    const float* __restrict__ bq, const float* __restrict__ bk,
    const float* __restrict__ bv, const float* __restrict__ bs,
    const float* __restrict__ bns, const float* __restrict__ gamma,
    const float* __restrict__ beta,
    _Float16* __restrict__ qo, unsigned int* __restrict__ kvb, float* __restrict__ xro)
{
    __shared__ _Float16 xs[64][136];
    __shared__ float ab_s[256];
    __shared__ float bsum[256];
    int t = threadIdx.x;
    float s = 0.f;
    for (int k = 0; k < NSLOT; ++k) s += bns[k * 256 + t];   // coalesced, L2-hot
    bsum[t] = s;
    __syncthreads();
    if (t < 128) {
        float mu = bsum[t] * (1.f / NN);
        float var = bsum[128 + t] * (1.f / NN) - mu * mu;
        float inv = rsqrtf(var + 1e-5f);
        float a = inv * gamma[t];
        ab_s[t] = a;
        ab_s[128 + t] = beta[t] - mu * a;
    }
    __syncthreads();
    gemm_tile(X, wt, bq, bk, bv, bs, ab_s, 1, xs, qo, kvb, xro, blockIdx.x * 64);
}

// 16-lane (per-head) sum via DPP row rotations — VALU-only, no DS-pipe ops.
__device__ __forceinline__ float row_sum16(float p) {
    p += __int_as_float(__builtin_amdgcn_update_dpp(0, __float_as_int(p), 0x128, 0xF, 0xF, true)); // row_ror:8
    p += __int_as_float(__builtin_amdgcn_update_dpp(0, __float_as_int(p), 0x124, 0xF, 0xF, true)); // row_ror:4
    p += __int_as_float(__builtin_amdgcn_update_dpp(0, __float_as_int(p), 0x122, 0xF, 0xF, true)); // row_ror:2
    p += __int_as_float(__builtin_amdgcn_update_dpp(0, __float_as_int(p), 0x121, 0xF, 0xF, true)); // row_ror:1
    return p;
}

// ---------------- attention + gate + BN-stats (one wave per dst node) ----------------
// v10: BN partials go straight into 64-slot atomic accumulators bns[64][256]
// (slot = blockIdx&63; 3.2M atomics over 1024 lines = ~9us serialization floor,
// hidden under the kernel — R4's disaster was 16 lines). Kills k_bnred + 12.8MB
// write + 12.8MB read per layer. Rest identical to v9.
__global__ __launch_bounds__(256) void k_attn(
    const _Float16* __restrict__ q, const unsigned int* __restrict__ kvb,
    const float* __restrict__ xr,
    const u64* __restrict__ erec,
    const int* __restrict__ row_ptr,
    const float* __restrict__ We, const float* __restrict__ be,
    const float* __restrict__ Wb,
    float* __restrict__ out2, float* __restrict__ bns)
{
    __shared__ u64 es[4][64];
    int t = threadIdx.x;
    int lane = t & 63;
    int wid = t >> 6;
    int n = blockIdx.x * 4 + wid;          // one node per wave, exact cover
    int ch = lane * 2;
    float2 we0 = *(const float2*)&We[ch];
    float2 we1 = *(const float2*)&We[128 + ch];
    float2 beL = *(const float2*)&be[ch];
    const float S2 = 0.17677669529663687f * 1.4426950408889634f;  // (1/sqrt(32))*log2(e)

    int rs = __builtin_amdgcn_readfirstlane(row_ptr[n]);
    int re = __builtin_amdgcn_readfirstlane(row_ptr[n + 1]);
    half2v qh = *(const half2v*)&q[(size_t)n * 128 + ch];
    float2 xv = *(const float2*)&xr[(size_t)n * 128 + ch];   // prefetch early
    float2 qs; qs.x = (float)qh[0] * S2; qs.y = (float)qh[1] * S2;
    float qw0 = qs.x * we0.x + qs.y * we0.y;
    float qw1 = qs.x * we1.x + qs.y * we1.y;
    float qb0 = qs.x * beL.x + qs.y * beL.y;
    float den = 0.f, sA = 0.f, sB = 0.f, ax = 0.f, ay = 0.f;

    for (int cb = rs; cb < re; cb += 64) {
        int cnum = re - cb; if (cnum > 64) cnum = 64;
        int mi = cb + lane;
        if (mi < re) es[wid][lane] = erec[mi];   // coalesced 8B; same-wave LDS in order
        const unsigned int* es32 = (const unsigned int*)&es[wid][0];
        int cm1 = cnum - 1;
        int ng = (cnum + 7) >> 3;                // padded groups of 8 (clamp+mask)
        unsigned int kkA[8], kkB[8];

#define LOAD8(KK, B0) do {                                                   \
        _Pragma("unroll")                                                    \
        for (int j = 0; j < 8; j++) {                                        \
            int o = (B0) + j; int oc = o < cm1 ? o : cm1;                    \
            unsigned int s = es32[oc * 2];                                   \
            KK[j] = kvb[(size_t)s * 64 + lane];                              \
        }                                                                    \
    } while (0)

#define COMP8(KK, B0) do {                                                   \
        _Pragma("unroll")                                                    \
        for (int j = 0; j < 8; j++) {                                        \
            int o = (B0) + j; int oc = o < cm1 ? o : cm1;                    \
            union { unsigned int u; _Float16 h[2]; } cv;                     \
            cv.u = es32[oc * 2 + 1];                                         \
            float eax = (float)cv.h[0], eay = (float)cv.h[1];                \
            auto kf = __builtin_amdgcn_cvt_pk_f32_fp8((int)KK[j], false);    \
            auto vf = __builtin_amdgcn_cvt_pk_f32_fp8((int)KK[j], true);     \
            float p = qs.x * kf[0];                                          \
            p = fmaf(qs.y, kf[1], p);                                        \
            p = fmaf(eax, qw0, p);                                           \
            p = fmaf(eay, qw1, p);                                           \
            p += qb0;                                                        \
            p = row_sum16(p);                                                \
            float exv = (o < cnum) ? __builtin_amdgcn_exp2f(p) : 0.f;        \
            den += exv;                                                      \
            sA = fmaf(exv, eax, sA);                                         \
            sB = fmaf(exv, eay, sB);                                         \
            ax = fmaf(exv, vf[0], ax);                                       \
            ay = fmaf(exv, vf[1], ay);                                       \
        }                                                                    \
    } while (0)

        LOAD8(kkA, 0);
        __builtin_amdgcn_sched_barrier(0);
        int g = 0;
        for (;;) {
            if (g + 1 < ng) { LOAD8(kkB, (g + 1) * 8); __builtin_amdgcn_sched_barrier(0); }
            COMP8(kkA, g * 8);
            ++g; if (g >= ng) break;
            if (g + 1 < ng) { LOAD8(kkA, (g + 1) * 8); __builtin_amdgcn_sched_barrier(0); }
            COMP8(kkB, g * 8);
            ++g; if (g >= ng) break;
        }
#undef LOAD8
#undef COMP8
    }

    // fold Sum(w*e) back in
    float axT = ax + sA * we0.x + sB * we1.x + den * beL.x;
    float ayT = ay + sA * we0.y + sB * we1.y + den * beL.y;
    float rden = 1.f / (den + 1e-16f);
    float axs = axT * rden, ays = ayT * rden;
    // beta gate
    float2 wb_o = *(const float2*)&Wb[ch];
    float2 wb_r = *(const float2*)&Wb[128 + ch];
    float2 wb_d = *(const float2*)&Wb[256 + ch];
    float gp = axs * wb_o.x + ays * wb_o.y + xv.x * wb_r.x + xv.y * wb_r.y
             + (axs - xv.x) * wb_d.x + (ays - xv.y) * wb_d.y;
    gp = row_sum16(gp);
    gp += __shfl_xor(gp, 16);
    gp += __shfl_xor(gp, 32);
    float gate = 1.f / (1.f + __expf(-gp));
    float ox = gate * xv.x + (1.f - gate) * axs;
    float oy = gate * xv.y + (1.f - gate) * ays;
    *(float2*)&out2[(size_t)n * 128 + ch] = make_float2(ox, oy);

    // block-level BN partial reduce -> 64-slot atomic accumulators
    __shared__ float s_sum[2][256], s_sq[2][256];
    s_sum[0][t] = ox; s_sum[1][t] = oy;
    s_sq[0][t] = ox * ox;  s_sq[1][t] = oy * oy;
    __syncthreads();
    if (t < 64) {
        float sx = s_sum[0][t] + s_sum[0][64 + t] + s_sum[0][128 + t] + s_sum[0][192 + t];
        float sy = s_sum[1][t] + s_sum[1][64 + t] + s_sum[1][128 + t] + s_sum[1][192 + t];
        float qx = s_sq[0][t] + s_sq[0][64 + t] + s_sq[0][128 + t] + s_sq[0][192 + t];
        float qy = s_sq[1][t] + s_sq[1][64 + t] + s_sq[1][128 + t] + s_sq[1][192 + t];
        float* bs = bns + (size_t)(blockIdx.x & (NSLOT - 1)) * 256;
        int c = 2 * t;
        atomicAdd(&bs[c], sx);
        atomicAdd(&bs[c + 1], sy);
        atomicAdd(&bs[128 + c], qx);
        atomicAdd(&bs[129 + c], qy);
    }
}

// ------- readout: BN stats from 64-slot partials, affine+ELU+dot(Wout);
//         LDS per-graph accumulate; FUSED final (last-block done counter) -------
__global__ __launch_bounds__(256) void k_pool(const float* __restrict__ x,
                                              const float* __restrict__ bns,
                                              const float* __restrict__ gamma,
                                              const float* __restrict__ beta,
                                              const float* __restrict__ Wout,
                                              const int* __restrict__ batch,
                                              float* __restrict__ gsum, int* __restrict__ gcnt,
                                              int* __restrict__ pdone,
                                              const float* __restrict__ bout,
                                              const float* __restrict__ obias,
                                              float* __restrict__ out) {
    __shared__ float lsum[NGRAPH];
    __shared__ int lcnt[NGRAPH];
    __shared__ float ab_s[256];
    __shared__ float bsum[256];
    __shared__ int lastf;
    int t = threadIdx.x;
    if (t < NGRAPH) { lsum[t] = 0.f; lcnt[t] = 0; }
    float s = 0.f;
    for (int k = 0; k < NSLOT; ++k) s += bns[k * 256 + t];
    bsum[t] = s;
    __syncthreads();
    if (t < 128) {
        float mu = bsum[t] * (1.f / NN);
        float var = bsum[128 + t] * (1.f / NN) - mu * mu;
        float inv = rsqrtf(var + 1e-5f);
        float a = inv * gamma[t];
        ab_s[t] = a;
        ab_s[128 + t] = beta[t] - mu * a;
    }
    __syncthreads();
    int lane = t & 63;
    int wid = t >> 6;
    int ch = lane * 2;
    float2 wo = *(const float2*)&Wout[ch];
    float2 a = *(const float2*)&ab_s[ch];
    float2 b = *(const float2*)&ab_s[128 + ch];
    for (int chunk = 0; chunk < 10; ++chunk) {
        int base = blockIdx.x * 160 + chunk * 16 + wid * 4;
        float2 xv[4];
#pragma unroll
        for (int i = 0; i < 4; i++) {          // issue all 4 loads before any use
            int n = base + i;
            xv[i] = (n < NN) ? *(const float2*)&x[(size_t)n * 128 + ch]
                             : make_float2(0.f, 0.f);
        }
#pragma unroll
        for (int i = 0; i < 4; i++) {
            int n = base + i;
            if (n < NN) {
                float z0 = fmaf(xv[i].x, a.x, b.x); z0 = z0 > 0.f ? z0 : expm1f(z0);
                float z1 = fmaf(xv[i].y, a.y, b.y); z1 = z1 > 0.f ? z1 : expm1f(z1);
                float p = z0 * wo.x + z1 * wo.y;
                p += __shfl_xor(p, 1);
                p += __shfl_xor(p, 2);
                p += __shfl_xor(p, 4);
                p += __shfl_xor(p, 8);
                p += __shfl_xor(p, 16);
                p += __shfl_xor(p, 32);
                if (lane == 0) {
                    int g = batch[n];
                    atomicAdd(&lsum[g], p);
                    atomicAdd(&lcnt[g], 1);
                }
            }
        }
    }
    __syncthreads();
    if (t < NGRAPH && lcnt[t] > 0) {
        atomicAdd(&gsum[t], lsum[t]);
        atomicAdd(&gcnt[t], lcnt[t]);
    }
    __threadfence();
    __syncthreads();
    if (t == 0) lastf = (atomicAdd(pdone, 1) == (int)gridDim.x - 1);
    __syncthreads();
    if (lastf && t < NGRAPH) {
        float gs = atomicAdd(&gsum[t], 0.f);   // atomic-read: force L2, skip stale L1
        int gc = atomicAdd(&gcnt[t], 0);
        out[t] = gs / fmaxf((float)gc, 1.f) + bout[0] + obias[0];
    }
}

extern "C" void kernel_launch(void* const* d_in, const int* in_sizes, int n_in,
                              void* d_out, int out_size, void* d_ws, size_t ws_size,
                              hipStream_t stream) {
    const float* x_in       = (const float*)d_in[0];
    const int* eidx         = (const int*)d_in[1];
    const float* eattr      = (const float*)d_in[2];
    const int* batch        = (const int*)d_in[3];
    const float* Wq         = (const float*)d_in[4];
    const float* bq         = (const float*)d_in[5];
    const float* Wk         = (const float*)d_in[6];
    const float* bk         = (const float*)d_in[7];
    const float* Wv         = (const float*)d_in[8];
    const float* bv         = (const float*)d_in[9];
    const float* We         = (const float*)d_in[10];
    const float* be         = (const float*)d_in[11];
    const float* Wskip      = (const float*)d_in[12];
    const float* bskip      = (const float*)d_in[13];
    const float* Wbeta      = (const float*)d_in[14];
    const float* bn_gamma   = (const float*)d_in[15];
    const float* bn_beta    = (const float*)d_in[16];
    const float* Wout       = (const float*)d_in[17];
    const float* bout       = (const float*)d_in[18];
    const float* obias      = (const float*)d_in[19];
    float* out = (float*)d_out;

    char* ws = (char*)d_ws;
    size_t off = 0;
    auto alloc = [&](size_t bytes) -> void* {
        off = (off + 255) & ~(size_t)255;
        void* p = ws + off;
        off += bytes;
        return p;
    };
    const size_t NF = (size_t)NN * 128 * sizeof(float);
    float* xbuf    = (float*)alloc(NF);
    _Float16* qb   = (_Float16*)alloc((size_t)NN * 128 * sizeof(_Float16));
    float* xrb     = (float*)alloc(NF);
    unsigned int* kvb = (unsigned int*)alloc((size_t)NN * 64 * sizeof(unsigned int));
    _Float16* wt   = (_Float16*)alloc((size_t)12 * 16384 * sizeof(_Float16));
    int* row_ptr   = (int*)alloc((NN + 1) * sizeof(int));
    int* cnt       = (int*)alloc(NN * sizeof(int));
    int* rank      = (int*)alloc(EE * sizeof(int));
    u64* erec      = (u64*)alloc((size_t)EE * sizeof(u64));
    float* bns3    = (float*)alloc((size_t)3 * NSLOT * 256 * sizeof(float));
    float* gsum    = (float*)alloc(64 * sizeof(float));
    int* gcnt      = (int*)alloc(64 * sizeof(int));
    int* pdone     = (int*)alloc(sizeof(int));
    (void)ws_size; (void)n_in; (void)in_sizes; (void)out_size;

    // ---- CSR degree + rank + weight prep, scan (also zeroes aux) ----
    hipMemsetAsync(cnt, 0, NN * sizeof(int), stream);
    k_degprep<<<3125 + 768, 256, 0, stream>>>(eidx, cnt, rank, Wq, Wk, Wv, Wskip, wt);
    k_scan<<<1, 1024, 0, stream>>>(cnt, row_ptr, bns3, gsum, gcnt, pdone);

    // ---- layer 0 GEMM + CSR scatter fused (independent work) ----
    k_gemm0scat<<<GEMM_TILES + 3125, 256, 0, stream>>>(
        x_in, wt, bq, bk, bv, bskip, qb, kvb, xrb,
        eidx, eattr, row_ptr, rank, erec);
    k_attn<<<NB_ATTN, 256, 0, stream>>>(
        qb, kvb, xrb, erec, row_ptr,
        We, be, Wbeta, xbuf, bns3);

    // ---- layers 1,2 ----
    for (int l = 1; l < 3; ++l) {
        k_gemm4<<<GEMM_TILES, 256, 0, stream>>>(
            xbuf, wt + (size_t)l * 65536,
            bq + l * 128, bk + l * 128, bv + l * 128, bskip + l * 128,
            bns3 + (size_t)(l - 1) * NSLOT * 256,
            bn_gamma + (l - 1) * 128, bn_beta + (l - 1) * 128,
            qb, kvb, xrb);
        k_attn<<<NB_ATTN, 256, 0, stream>>>(
            qb, kvb, xrb, erec, row_ptr,
            We + (size_t)l * 256, be + l * 128, Wbeta + (size_t)l * 384,
            xbuf, bns3 + (size_t)l * NSLOT * 256);
    }

    // ---- readout (BN affine+ELU of layer-2 + final fused in) ----
    k_pool<<<313, 256, 0, stream>>>(xbuf, bns3 + (size_t)2 * NSLOT * 256,
                                    bn_gamma + 2 * 128, bn_beta + 2 * 128,
                                    Wout, batch, gsum, gcnt, pdone, bout, obias, out);
}